// Round 3
// baseline (266.142 us; speedup 1.0000x reference)
//
#include <hip/hip_runtime.h>
#include <math.h>

// Problem constants
#define NB   512   // B
#define NH   64    // H = E = HP
#define OBS  8
#define PRE  12

// small f32 param pack offsets (elements)
#define OFF_WREL  0     // 128
#define OFF_BREL  128   // 64
#define OFF_BPOOL 192   // 64
#define OFF_WPOS  256   // 128
#define OFF_BPOS  384   // 2
#define OFF_WEMB  386   // 128
#define OFF_BEMB  514   // 64
#define OFF_BIH   578   // 192
#define OFF_BHH   770   // 192
#define OFF_FLAG  962   // 1: 1.0 if buffers are f32, 0.0 if bf16
#define N_SMALL   963

typedef __bf16 bf16x8 __attribute__((ext_vector_type(8)));
typedef float  f32x4  __attribute__((ext_vector_type(4)));

union FragU { bf16x8 v; unsigned short u[8]; };

__device__ __forceinline__ float bf2f(unsigned short u) {
  unsigned int x = ((unsigned int)u) << 16;
  return __builtin_bit_cast(float, x);
}
__device__ __forceinline__ unsigned short f2bf(float f) {
  unsigned int u = __builtin_bit_cast(unsigned int, f);
  u += 0x7FFFu + ((u >> 16) & 1u);   // RNE
  return (unsigned short)(u >> 16);
}
// dtype-branched accessors (flag uniform per wave -> no divergence cost)
__device__ __forceinline__ float ldf(const void* p, int i, bool isf32) {
  return isf32 ? ((const float*)p)[i] : bf2f(((const unsigned short*)p)[i]);
}
__device__ __forceinline__ unsigned short ld16(const void* p, int i, bool isf32) {
  return isf32 ? f2bf(((const float*)p)[i]) : ((const unsigned short*)p)[i];
}
__device__ __forceinline__ void stout(void* p, int i, float v, bool isf32) {
  if (isf32) ((float*)p)[i] = v;
  else       ((unsigned short*)p)[i] = f2bf(v);
}

// ---------------------------------------------------------------------------
// Prep: detect input dtype (f32 vs bf16), canonicalize all inputs into ws,
// copy observed track to out, seed last/h state, transpose GRU weights.
// grid: 512 blocks x 64 threads (1 wave/block)
// ---------------------------------------------------------------------------
__global__ __launch_bounds__(64) void prep_kernel(
    const void* __restrict__ hidden_state, // (1,512,64)
    const void* __restrict__ group_track,  // (512,8,2)
    const void* __restrict__ W_emb,  const void* __restrict__ b_emb,
    const void* __restrict__ W_ih,   const void* __restrict__ W_hh,
    const void* __restrict__ b_ih,   const void* __restrict__ b_hh,
    const void* __restrict__ W_pos,  const void* __restrict__ b_pos,
    const void* __restrict__ W_rel,  const void* __restrict__ b_rel,
    const void* __restrict__ W_pool, const void* __restrict__ b_pool,
    float* __restrict__ last0,             // (512,2) f32
    unsigned short* __restrict__ hbf0,     // (512,64) bf16 spool-h
    float* __restrict__ h_carry,           // (512,64) f32 GRU carry
    float* __restrict__ WTf,               // (64,384) f32 transposed GRU W
    unsigned short* __restrict__ Wp_bf,    // (128,64) bf16 W_pool
    float* __restrict__ smallf,            // N_SMALL f32 param pack
    void* __restrict__ out)                // (512,20,2) output dtype = input dtype
{
  const int b = blockIdx.x;
  const int o = threadIdx.x;

  // ---- dtype detect: bf16-interpret first 256 u16 of hidden_state.
  // If data is f32, mantissa-low halves are ~uniform u16 -> exponent>=0x8E
  // (|v|>=2^15) trips with prob ~1 - 1e-33. bf16 N(0,1) data never trips.
  int bad = 0;
  const unsigned short* hs16 = (const unsigned short*)hidden_state;
  for (int k = o; k < 256; k += 64) {
    unsigned e = (hs16[k] >> 7) & 0xFFu;
    bad |= (e >= 0x8Eu) ? 1 : 0;
  }
  const bool isf32 = (__ballot(bad) != 0ULL);   // wave-uniform

  // ---- per-agent state
  hbf0[b * 64 + o] = ld16(hidden_state, b * 64 + o, isf32);
  h_carry[b * 64 + o] = 0.0f;
  if (o < 16) stout(out, b * 40 + o, ldf(group_track, b * 16 + o, isf32), isf32);
  if (o < 2)  last0[b * 2 + o] = ldf(group_track, b * 16 + 14 + o, isf32);

  // ---- transposed GRU weights, f32: WTf[k*384+c] = (c<192 ? W_ih : W_hh)[c%192][k]
  if (b < 384) {
    int u = b * 64 + o;             // [0, 24576)
    int k = u / 384, c = u % 384;
    WTf[u] = (c < 192) ? ldf(W_ih, c * 64 + k, isf32)
                       : ldf(W_hh, (c - 192) * 64 + k, isf32);
  } else {
    int u = (b - 384) * 64 + o;     // [0, 8192)
    Wp_bf[u] = ld16(W_pool, u, isf32);
  }

  // ---- small param pack (f32)
  if (b < 16) {
    int u = b * 64 + o;
    if (u < N_SMALL) {
      float v;
      if      (u < 128) v = ldf(W_rel,  u,        isf32);
      else if (u < 192) v = ldf(b_rel,  u - 128,  isf32);
      else if (u < 256) v = ldf(b_pool, u - 192,  isf32);
      else if (u < 384) v = ldf(W_pos,  u - 256,  isf32);
      else if (u < 386) v = ldf(b_pos,  u - 384,  isf32);
      else if (u < 514) v = ldf(W_emb,  u - 386,  isf32);
      else if (u < 578) v = ldf(b_emb,  u - 514,  isf32);
      else if (u < 770) v = ldf(b_ih,   u - 578,  isf32);
      else if (u < 962) v = ldf(b_hh,   u - 770,  isf32);
      else              v = isf32 ? 1.0f : 0.0f;   // OFF_FLAG
      smallf[u] = v;
    }
  }
}

// ---------------------------------------------------------------------------
// One decoder iteration: social pool (MFMA) + pos/emb/GRU head, block = one i
// grid: 512 blocks x 256 threads (4 waves, each 128 j rows)
// ---------------------------------------------------------------------------
__global__ __launch_bounds__(256) void pair_kernel(
    const float* __restrict__ smallf,
    const unsigned short* __restrict__ Wp_bf,   // (128,64) bf16
    const float* __restrict__ WTf,              // (64,384) f32
    const float* __restrict__ last_in,          // (512,2) f32
    float* __restrict__ last_out,               // (512,2) f32
    const unsigned short* __restrict__ hbf_in,  // (512,64) bf16
    unsigned short* __restrict__ hbf_out,       // (512,64) bf16
    float* __restrict__ h_carry,                // (512,64) f32
    void* __restrict__ out,                     // (512,20,2) detected dtype
    int t)
{
  const int i    = blockIdx.x;
  const int tid  = threadIdx.x;
  const int lane = tid & 63;
  const int wave = tid >> 6;
  const int col  = lane & 15;   // MFMA m (A rows) / n (B cols) index
  const int quad = lane >> 4;   // selects k-group (quad*8 .. quad*8+7)

  __shared__ float red[4][64];

  const float2* lp = (const float2*)last_in;
  const float2  li = lp[i];

  // --- per-lane W_rel / b_rel values for k = ks*32 + quad*8 + j ------------
  float wr0[2][8], wr1[2][8], brl[2][8];
  #pragma unroll
  for (int ks = 0; ks < 2; ++ks) {
    int kb = ks * 32 + quad * 8;
    #pragma unroll
    for (int j = 0; j < 8; ++j) {
      wr0[ks][j] = smallf[OFF_WREL + kb + j];
      wr1[ks][j] = smallf[OFF_WREL + 64 + kb + j];
      brl[ks][j] = smallf[OFF_BREL + kb + j];
    }
  }
  float bp[4];
  #pragma unroll
  for (int nt = 0; nt < 4; ++nt) bp[nt] = smallf[OFF_BPOOL + nt * 16 + col];

  // --- B-operand fragments of full W_pool (K=128): lane holds
  //     B[k = ks*32 + quad*8 + j][n = nt*16 + col] ----------------------------
  FragU bw[4][4];
  #pragma unroll
  for (int nt = 0; nt < 4; ++nt)
    #pragma unroll
    for (int ks = 0; ks < 4; ++ks)
      #pragma unroll
      for (int j = 0; j < 8; ++j)
        bw[nt][ks].u[j] = Wp_bf[(ks * 32 + quad * 8 + j) * 64 + nt * 16 + col];

  float vmax[4] = {0.f, 0.f, 0.f, 0.f};  // m = relu(..) >= 0, so 0 is safe

  // --- j loop: this wave covers rows [wave*128, wave*128+128), 32 at a time --
  const int jb0 = wave * 128;
  for (int s = 0; s < 4; ++s) {
    const int jb = jb0 + s * 32;
    const int r0 = jb + col, r1 = r0 + 16;
    const float2 l0 = lp[r0], l1 = lp[r1];
    const float d0x = l0.x - li.x, d0y = l0.y - li.y;
    const float d1x = l1.x - li.x, d1y = l1.y - li.y;

    // A-fragments for e-part (K rows 0..63): computed in registers, frag layout
    FragU aE[2][2];
    #pragma unroll
    for (int ks = 0; ks < 2; ++ks) {
      #pragma unroll
      for (int j = 0; j < 8; ++j) {
        float e0 = fmaxf(d0x * wr0[ks][j] + d0y * wr1[ks][j] + brl[ks][j], 0.f);
        float e1 = fmaxf(d1x * wr0[ks][j] + d1y * wr1[ks][j] + brl[ks][j], 0.f);
        aE[0][ks].u[j] = f2bf(e0);
        aE[1][ks].u[j] = f2bf(e1);
      }
    }
    // A-fragments for h-part (K rows 64..127): vector loads from bf16 h matrix
    bf16x8 aH[2][2];
    #pragma unroll
    for (int mt = 0; mt < 2; ++mt) {
      int jr = jb + mt * 16 + col;
      #pragma unroll
      for (int ks = 0; ks < 2; ++ks)
        aH[mt][ks] = *(const bf16x8*)(hbf_in + jr * 64 + ks * 32 + quad * 8);
    }

    f32x4 acc[2][4];
    #pragma unroll
    for (int mt = 0; mt < 2; ++mt)
      #pragma unroll
      for (int nt = 0; nt < 4; ++nt)
        acc[mt][nt] = (f32x4){0.f, 0.f, 0.f, 0.f};

    #pragma unroll
    for (int nt = 0; nt < 4; ++nt)
      #pragma unroll
      for (int mt = 0; mt < 2; ++mt) {
        acc[mt][nt] = __builtin_amdgcn_mfma_f32_16x16x32_bf16(aE[mt][0].v, bw[nt][0].v, acc[mt][nt], 0, 0, 0);
        acc[mt][nt] = __builtin_amdgcn_mfma_f32_16x16x32_bf16(aE[mt][1].v, bw[nt][1].v, acc[mt][nt], 0, 0, 0);
        acc[mt][nt] = __builtin_amdgcn_mfma_f32_16x16x32_bf16(aH[mt][0],   bw[nt][2].v, acc[mt][nt], 0, 0, 0);
        acc[mt][nt] = __builtin_amdgcn_mfma_f32_16x16x32_bf16(aH[mt][1],   bw[nt][3].v, acc[mt][nt], 0, 0, 0);
      }

    // epilogue: + b_pool, relu, running max over rows (fuses to v_max3)
    #pragma unroll
    for (int mt = 0; mt < 2; ++mt)
      #pragma unroll
      for (int nt = 0; nt < 4; ++nt)
        #pragma unroll
        for (int r = 0; r < 4; ++r) {
          float v = acc[mt][nt][r] + bp[nt];
          vmax[nt] = fmaxf(fmaxf(v, 0.f), vmax[nt]);
        }
  }

  // reduce over quads (rows) within the wave, then across waves via LDS
  #pragma unroll
  for (int nt = 0; nt < 4; ++nt) {
    vmax[nt] = fmaxf(vmax[nt], __shfl_xor(vmax[nt], 16, 64));
    vmax[nt] = fmaxf(vmax[nt], __shfl_xor(vmax[nt], 32, 64));
  }
  if (lane < 16) {
    #pragma unroll
    for (int nt = 0; nt < 4; ++nt) red[wave][nt * 16 + lane] = vmax[nt];
  }
  __syncthreads();

  // ---------------- head: pos -> emb -> GRU -> new state (wave 0 only) -----
  if (tid < 64) {
    const int o = tid;
    const bool isf32 = (smallf[OFF_FLAG] != 0.0f);
    float pooled = fmaxf(fmaxf(red[0][o], red[1][o]), fmaxf(red[2][o], red[3][o]));
    float p0 = pooled * smallf[OFF_WPOS + o * 2 + 0];
    float p1 = pooled * smallf[OFF_WPOS + o * 2 + 1];
    #pragma unroll
    for (int sft = 32; sft >= 1; sft >>= 1) {
      p0 += __shfl_xor(p0, sft, 64);
      p1 += __shfl_xor(p1, sft, 64);
    }
    p0 += smallf[OFF_BPOS + 0];
    p1 += smallf[OFF_BPOS + 1];
    if (o == 0) {
      stout(out, i * 40 + (OBS + t) * 2 + 0, p0, isf32);
      stout(out, i * 40 + (OBS + t) * 2 + 1, p1, isf32);
      last_out[2 * i]     = p0;
      last_out[2 * i + 1] = p1;
    }
    // GRU: lane o computes gate element o of each of the 6 mat-vecs
    float gir = 0.f, giz = 0.f, gin = 0.f, ghr = 0.f, ghz = 0.f, ghn = 0.f;
    #pragma unroll 8
    for (int k = 0; k < 64; ++k) {
      float ek = p0 * smallf[OFF_WEMB + k] + p1 * smallf[OFF_WEMB + 64 + k]
               + smallf[OFF_BEMB + k];            // emb_k (uniform)
      float hk = h_carry[i * 64 + k];             // uniform
      const float* w = WTf + k * 384;             // coalesced across lanes
      gir += ek * w[o];
      giz += ek * w[64 + o];
      gin += ek * w[128 + o];
      ghr += hk * w[192 + o];
      ghz += hk * w[256 + o];
      ghn += hk * w[320 + o];
    }
    gir += smallf[OFF_BIH + o];       ghr += smallf[OFF_BHH + o];
    giz += smallf[OFF_BIH + 64 + o];  ghz += smallf[OFF_BHH + 64 + o];
    gin += smallf[OFF_BIH + 128 + o]; ghn += smallf[OFF_BHH + 128 + o];
    float r = 1.f / (1.f + __expf(-(gir + ghr)));
    float z = 1.f / (1.f + __expf(-(giz + ghz)));
    float n = tanhf(gin + r * ghn);
    float hp = h_carry[i * 64 + o];
    float hn = (1.f - z) * n + z * hp;
    h_carry[i * 64 + o] = hn;          // program-order after all reads above
    hbf_out[i * 64 + o] = f2bf(hn);
  }
}

// ---------------------------------------------------------------------------
extern "C" void kernel_launch(void* const* d_in, const int* in_sizes, int n_in,
                              void* d_out, int out_size, void* d_ws, size_t ws_size,
                              hipStream_t stream) {
  (void)in_sizes; (void)n_in; (void)out_size; (void)ws_size;
  const void* hidden_state = d_in[0];
  const void* group_track  = d_in[1];
  const void* W_emb  = d_in[2];
  const void* b_emb  = d_in[3];
  const void* W_ih   = d_in[4];
  const void* W_hh   = d_in[5];
  const void* b_ih   = d_in[6];
  const void* b_hh   = d_in[7];
  const void* W_pos  = d_in[8];
  const void* b_pos  = d_in[9];
  const void* W_rel  = d_in[10];
  const void* b_rel  = d_in[11];
  const void* W_pool = d_in[12];
  const void* b_pool = d_in[13];

  char* ws = (char*)d_ws;
  float* last[2]          = {(float*)(ws + 0),      (float*)(ws + 4096)};
  unsigned short* hbf[2]  = {(unsigned short*)(ws + 8192),
                             (unsigned short*)(ws + 73728)};
  float* h_carry          = (float*)(ws + 139264);
  float* WTf              = (float*)(ws + 270336);          // 98304 B
  unsigned short* Wp_bf   = (unsigned short*)(ws + 368640); // 16384 B
  float* smallf           = (float*)(ws + 385024);          // ~3856 B
  // total ws use: ~388,880 bytes

  prep_kernel<<<512, 64, 0, stream>>>(hidden_state, group_track,
                                      W_emb, b_emb, W_ih, W_hh, b_ih, b_hh,
                                      W_pos, b_pos, W_rel, b_rel, W_pool, b_pool,
                                      last[0], hbf[0], h_carry, WTf, Wp_bf,
                                      smallf, d_out);
  for (int t = 0; t < PRE; ++t) {
    int p = t & 1;
    pair_kernel<<<512, 256, 0, stream>>>(smallf, Wp_bf, WTf,
                                         last[p], last[1 - p],
                                         hbf[p], hbf[1 - p],
                                         h_carry, d_out, t);
  }
}